// Round 1
// baseline (1242.906 us; speedup 1.0000x reference)
//
#include <hip/hip_runtime.h>
#include <math.h>

#define EPS 1e-5f

typedef __bf16 bf16x8 __attribute__((ext_vector_type(8)));
typedef __bf16 bf16x4 __attribute__((ext_vector_type(4)));
typedef float  f32x4  __attribute__((ext_vector_type(4)));

constexpr int D  = 1024;   // hidden dim (fixed by the reference)
constexpr int BM = 128;    // M tile
constexpr int BN = 128;    // N tile
constexpr int BK = 32;     // K tile (one 16x16x32 MFMA deep)
constexpr int LDT = BK + 8; // padded LDS row stride (40 bf16 = 80 B, 16B-aligned)

// ---------------------------------------------------------------------------
// Per-row raw sum-of-squares -> projection scale s = min((1-eps)/(norm+1e-10),1)
// store s and projected squared-norm s^2 * sumsq.
// One 256-thread block per row; 256*4 = 1024 = D floats per row.
// ---------------------------------------------------------------------------
__global__ __launch_bounds__(256) void row_stats_kernel(
    const float* __restrict__ src, float* __restrict__ scale_out,
    float* __restrict__ sq_out)
{
    const int row = blockIdx.x;
    const int t = threadIdx.x;
    const float4 v = *(const float4*)(src + (size_t)row * D + t * 4);
    float s = v.x * v.x + v.y * v.y + v.z * v.z + v.w * v.w;
#pragma unroll
    for (int off = 32; off > 0; off >>= 1) s += __shfl_down(s, off);
    __shared__ float partial[4];
    if ((t & 63) == 0) partial[t >> 6] = s;
    __syncthreads();
    if (t == 0) {
        float tot = partial[0] + partial[1] + partial[2] + partial[3];
        float norm = sqrtf(tot);
        float sc = fminf((1.0f - EPS) / (norm + 1e-10f), 1.0f);
        scale_out[row] = sc;
        sq_out[row] = sc * sc * tot;
    }
}

// ---------------------------------------------------------------------------
// GEMM on raw fp32 inputs (converted to bf16 in the staging path) with fused
// hyperbolic-distance epilogue.
//   grid = (V/BN, N/BM), block = 256 (4 waves, each 64x64 via 4x4 16x16 frags)
// ---------------------------------------------------------------------------
__global__ __launch_bounds__(256) void hyp_gemm_kernel(
    const float* __restrict__ X, const float* __restrict__ Y,
    const float* __restrict__ sx, const float* __restrict__ xq,
    const float* __restrict__ sy, const float* __restrict__ yq,
    float* __restrict__ out, int V)
{
    __shared__ __bf16 As[BM * LDT];
    __shared__ __bf16 Bs[BN * LDT];

    const int t  = threadIdx.x;
    const int m0 = blockIdx.y * BM;
    const int n0 = blockIdx.x * BN;

    // staging map: thread t covers rows (t>>3)+32j (j=0..3), float4-col t&7
    const int sr = t >> 3;
    const int scol = t & 7;

    const float* xg = X + (size_t)(m0 + sr) * D + scol * 4;
    const float* yg = Y + (size_t)(n0 + sr) * D + scol * 4;

    const int lane = t & 63;
    const int wave = t >> 6;
    const int wm = (wave & 1) * 64;
    const int wn = (wave >> 1) * 64;
    const int ln = lane & 15;
    const int quad = lane >> 4;

    f32x4 acc[4][4] = {};

    // prefetch K-tile 0 into registers
    float4 pa[4], pb[4];
#pragma unroll
    for (int j = 0; j < 4; ++j) {
        pa[j] = *(const float4*)(xg + (size_t)j * 32 * D);
        pb[j] = *(const float4*)(yg + (size_t)j * 32 * D);
    }

    constexpr int KT = D / BK;  // 32 iterations
    for (int kt = 0; kt < KT; ++kt) {
        __syncthreads();  // previous iter's frag reads done before overwrite
#pragma unroll
        for (int j = 0; j < 4; ++j) {
            bf16x4 a4 = { (__bf16)pa[j].x, (__bf16)pa[j].y, (__bf16)pa[j].z, (__bf16)pa[j].w };
            bf16x4 b4 = { (__bf16)pb[j].x, (__bf16)pb[j].y, (__bf16)pb[j].z, (__bf16)pb[j].w };
            *(bf16x4*)&As[(sr + 32 * j) * LDT + scol * 4] = a4;
            *(bf16x4*)&Bs[(sr + 32 * j) * LDT + scol * 4] = b4;
        }
        __syncthreads();
        if (kt + 1 < KT) {   // prefetch next K-tile; overlaps with MFMA below
            const int koff = (kt + 1) * BK;
#pragma unroll
            for (int j = 0; j < 4; ++j) {
                pa[j] = *(const float4*)(xg + (size_t)j * 32 * D + koff);
                pb[j] = *(const float4*)(yg + (size_t)j * 32 * D + koff);
            }
        }
        bf16x8 af[4], bfr[4];
#pragma unroll
        for (int i = 0; i < 4; ++i) {
            af[i]  = *(const bf16x8*)&As[(wm + i * 16 + ln) * LDT + quad * 8];
            bfr[i] = *(const bf16x8*)&Bs[(wn + i * 16 + ln) * LDT + quad * 8];
        }
#pragma unroll
        for (int mt = 0; mt < 4; ++mt)
#pragma unroll
            for (int nt = 0; nt < 4; ++nt)
                acc[mt][nt] = __builtin_amdgcn_mfma_f32_16x16x32_bf16(
                    af[mt], bfr[nt], acc[mt][nt], 0, 0, 0);
    }

    // ---------------- epilogue: hyperbolic distance ----------------
    // C/D layout: col = lane&15, row = quad*4 + reg  [m89-verified]
    float yqv[4], syv[4];
    int gcv[4];
#pragma unroll
    for (int nt = 0; nt < 4; ++nt) {
        const int gc = n0 + wn + nt * 16 + ln;
        gcv[nt] = gc;
        yqv[nt] = yq[gc];
        syv[nt] = sy[gc];
    }
#pragma unroll
    for (int mt = 0; mt < 4; ++mt) {
#pragma unroll
        for (int r = 0; r < 4; ++r) {
            const int gm = m0 + wm + mt * 16 + quad * 4 + r;
            const float xqv = xq[gm];
            const float sxv = sx[gm];
            const float omx = 1.0f - xqv;
            float* orow = out + (size_t)gm * V;
#pragma unroll
            for (int nt = 0; nt < 4; ++nt) {
                const float raw = acc[mt][nt][r];
                const float dot = sxv * syv[nt] * raw;      // projected x.y
                float d2 = xqv + yqv[nt] - 2.0f * dot;
                float dd = __builtin_amdgcn_sqrtf(fmaxf(d2, 0.0f));
                float denom = omx * (1.0f - yqv[nt]) + EPS;
                float arg = 1.0f + 2.0f * dd * __builtin_amdgcn_rcpf(denom);
                arg = fmaxf(arg, 1.0f + EPS);
                // arccosh(z) = log(z + sqrt(z^2 - 1)), z up to ~3e5: fp32-safe
                float res = -__logf(arg + __builtin_amdgcn_sqrtf(arg * arg - 1.0f));
                orow[gcv[nt]] = res;
            }
        }
    }
}

// ---------------------------------------------------------------------------
extern "C" void kernel_launch(void* const* d_in, const int* in_sizes, int n_in,
                              void* d_out, int out_size, void* d_ws, size_t ws_size,
                              hipStream_t stream)
{
    const float* X = (const float*)d_in[0];   // hidden_states (N x D) fp32
    const float* Y = (const float*)d_in[1];   // weight        (V x D) fp32
    float* out = (float*)d_out;               // logits (N x V) fp32

    const int N = in_sizes[0] / D;   // 4096
    const int V = in_sizes[1] / D;   // 32000

    // workspace: 2*(N+V) floats = 288 KB
    float* sx = (float*)d_ws;
    float* xq = sx + N;
    float* sy = xq + N;
    float* yq = sy + V;

    row_stats_kernel<<<N, 256, 0, stream>>>(X, sx, xq);
    row_stats_kernel<<<V, 256, 0, stream>>>(Y, sy, yq);

    dim3 grid(V / BN, N / BM);
    hyp_gemm_kernel<<<grid, 256, 0, stream>>>(X, Y, sx, xq, sy, yq, out, V);
}